// Round 4
// baseline (2267.415 us; speedup 1.0000x reference)
//
#include <hip/hip_runtime.h>
#include <math.h>

#define LL  3
#define EE  1000000
#define NNODE 100000
#define DD  64
#define AAT 8
#define NR2C 461
#define QQ  1000
#define ENTC 10000
#define QE  (QQ * ENTC)
#define SCAN_NB 98   // ceil(NNODE/1024)

__device__ __forceinline__ float sigmoidf_(float x) {
    return 1.0f / (1.0f + __expf(-x));
}
__device__ __forceinline__ float tanhf_(float x) {
    return 1.0f - 2.0f / (__expf(2.0f * x) + 1.0f);
}

// Butterfly: input p[a] = lane's partial for output a. Returns full dot for
// a = lane&7 (replicated across the eight 8-lane groups).
__device__ __forceinline__ float dot8_reduce(float* p, int lane) {
#pragma unroll
    for (int st = 1; st < 8; st <<= 1)
#pragma unroll
        for (int a = 0; a < 8; ++a)
            p[a] += __shfl_xor(p[a], st, 64);
    const int aid = lane & 7;
    float v = p[0];
#pragma unroll
    for (int j = 1; j < 8; ++j)
        v = (aid == j) ? p[j] : v;
    v += __shfl_xor(v, 8, 64);
    v += __shfl_xor(v, 16, 64);
    v += __shfl_xor(v, 32, 64);
    return v;
}

__global__ void fill_f32(float* __restrict__ p, int n, float v) {
    int i = blockIdx.x * blockDim.x + threadIdx.x;
    int stride = gridDim.x * blockDim.x;
    float4* p4 = (float4*)p;
    int n4 = n >> 2;
    float4 v4 = make_float4(v, v, v, v);
    for (int j = i; j < n4; j += stride) p4[j] = v4;
}

__global__ void fill_i32(int* __restrict__ p, int n, int v) {
    int i = blockIdx.x * blockDim.x + threadIdx.x;
    int stride = gridDim.x * blockDim.x;
    int4* p4 = (int4*)p;
    int n4 = n >> 2;
    int4 v4 = make_int4(v, v, v, v);
    for (int j = i; j < n4; j += stride) p4[j] = v4;
}

// r_att[r][a] = emb[r]@Wr^T  (r<461);  qr_att[j][a] = emb[relation[j]]@Wqr^T + b[a]
__global__ __launch_bounds__(256) void rqatt_kernel(
    const int* __restrict__ relation, const float* __restrict__ emb,
    const float* __restrict__ Wr, const float* __restrict__ Wqr,
    const float* __restrict__ Wqrb,
    float* __restrict__ r_att, float* __restrict__ qr_att)
{
    const int lane = threadIdx.x & 63;
    const int wid = (blockIdx.x * blockDim.x + threadIdx.x) >> 6;
    const int nw = (gridDim.x * blockDim.x) >> 6;
    float wr8[8], wq8[8];
#pragma unroll
    for (int a = 0; a < 8; ++a) {
        wr8[a] = Wr[a * 64 + lane];
        wq8[a] = Wqr[a * 64 + lane];
    }
    for (int i = wid; i < NR2C + QQ; i += nw) {
        const bool isQ = i >= NR2C;
        const int row = isQ ? relation[i - NR2C] : i;
        const float ev = emb[row * 64 + lane];
        float p[8];
#pragma unroll
        for (int a = 0; a < 8; ++a) p[a] = ev * (isQ ? wq8[a] : wr8[a]);
        float v = dot8_reduce(p, lane);
        if (lane < 8) {
            if (isQ) qr_att[(i - NR2C) * 8 + lane] = v + Wqrb[lane];
            else     r_att[i * 8 + lane] = v;
        }
    }
}

// alpha[e] = sigmoid( walpha . relu(s_att[sub]+r_att[rel]+qr_att[r_idx]) + wb )
// fused: counts[obj[e]] += 1  (histogram for CSR build)
__global__ __launch_bounds__(256) void alpha_hist_kernel(
    const int* __restrict__ sub, const int* __restrict__ rel,
    const int* __restrict__ r_idx, const int* __restrict__ obj,
    const float* __restrict__ s_att, const float* __restrict__ r_att,
    const float* __restrict__ qr_att,
    const float* __restrict__ walw, const float* __restrict__ walb,
    float* __restrict__ alpha, int* __restrict__ counts)
{
    const int e = blockIdx.x * blockDim.x + threadIdx.x;
    if (e >= EE) return;
    const float4* sa = (const float4*)(s_att + sub[e] * 8);
    const float4* ra = (const float4*)(r_att + rel[e] * 8);
    const float4* qa = (const float4*)(qr_att + r_idx[e] * 8);
    const float4 s0 = sa[0], s1 = sa[1];
    const float4 r0 = ra[0], r1 = ra[1];
    const float4 q0 = qa[0], q1 = qa[1];
    float t = walb[0];
    t += walw[0] * fmaxf(s0.x + r0.x + q0.x, 0.0f);
    t += walw[1] * fmaxf(s0.y + r0.y + q0.y, 0.0f);
    t += walw[2] * fmaxf(s0.z + r0.z + q0.z, 0.0f);
    t += walw[3] * fmaxf(s0.w + r0.w + q0.w, 0.0f);
    t += walw[4] * fmaxf(s1.x + r1.x + q1.x, 0.0f);
    t += walw[5] * fmaxf(s1.y + r1.y + q1.y, 0.0f);
    t += walw[6] * fmaxf(s1.z + r1.z + q1.z, 0.0f);
    t += walw[7] * fmaxf(s1.w + r1.w + q1.w, 0.0f);
    alpha[e] = sigmoidf_(t);
    atomicAdd(&counts[obj[e]], 1);
}

// CSR build: per-block exclusive scan of counts -> cursor; block sums -> partials
__global__ __launch_bounds__(1024) void scan_block_kernel(
    const int* __restrict__ counts, int* __restrict__ cursor,
    int* __restrict__ partials)
{
    __shared__ int buf[1024];
    const int tid = threadIdx.x;
    const int g = blockIdx.x * 1024 + tid;
    const int v = (g < NNODE) ? counts[g] : 0;
    buf[tid] = v;
    __syncthreads();
#pragma unroll
    for (int off = 1; off < 1024; off <<= 1) {
        int t = (tid >= off) ? buf[tid - off] : 0;
        __syncthreads();
        buf[tid] += t;
        __syncthreads();
    }
    if (g < NNODE) cursor[g] = buf[tid] - v;   // exclusive
    if (tid == 1023) partials[blockIdx.x] = buf[1023];
}

__global__ __launch_bounds__(128) void scan_partials_kernel(int* __restrict__ partials)
{
    __shared__ int buf[128];
    const int tid = threadIdx.x;
    const int v = (tid < SCAN_NB) ? partials[tid] : 0;
    buf[tid] = v;
    __syncthreads();
#pragma unroll
    for (int off = 1; off < 128; off <<= 1) {
        int t = (tid >= off) ? buf[tid - off] : 0;
        __syncthreads();
        buf[tid] += t;
        __syncthreads();
    }
    if (tid < SCAN_NB) partials[tid] = buf[tid] - v;  // exclusive
}

__global__ void scan_add_kernel(int* __restrict__ cursor, const int* __restrict__ partials)
{
    const int g = blockIdx.x * blockDim.x + threadIdx.x;
    if (g < NNODE) cursor[g] += partials[g >> 10];
}

// eidx[cursor[obj[e]]++] = e ; after this, cursor[n] = end offset of node n
__global__ void bucket_kernel(const int* __restrict__ obj,
                              int* __restrict__ cursor, int* __restrict__ eidx)
{
    const int e = blockIdx.x * blockDim.x + threadIdx.x;
    if (e < EE) {
        const int pos = atomicAdd(&cursor[obj[e]], 1);
        eidx[pos] = e;
    }
}

// agg[n] = sum over in-edges e: alpha[e] * (h[sub[e]] + emb[rel[e]])
// One wave per node. Lanes load up to 64 edges' metadata in parallel, then
// broadcast via readlane; the two gathers per edge pipeline across iterations.
__global__ __launch_bounds__(256) void aggregate_kernel(
    const int* __restrict__ sub, const int* __restrict__ rel,
    const int* __restrict__ eidx, const int* __restrict__ cursor_end,
    const int* __restrict__ counts, const float* __restrict__ alpha,
    const float* __restrict__ h, const float* __restrict__ emb,
    float* __restrict__ agg)
{
    const int lane = threadIdx.x & 63;
    const int n = (blockIdx.x * blockDim.x + threadIdx.x) >> 6;
    if (n >= NNODE) return;
    const int end = cursor_end[n];
    const int deg = counts[n];
    float acc = 0.0f;
    for (int j0 = end - deg; j0 < end; j0 += 64) {
        const int m = min(64, end - j0);
        int e = 0, s = 0, r = 0;
        float a = 0.0f;
        if (lane < m) e = eidx[j0 + lane];
        if (lane < m) { s = sub[e]; r = rel[e]; a = alpha[e]; }
        for (int t = 0; t < m; ++t) {
            const int st = __builtin_amdgcn_readlane(s, t);
            const int rt = __builtin_amdgcn_readlane(r, t);
            const float at = __int_as_float(__builtin_amdgcn_readlane(__float_as_int(a), t));
            acc = fmaf(at, h[st * 64 + lane] + emb[rt * 64 + lane], acc);
        }
    }
    agg[n * 64 + lane] = acc;
}

// Thread-per-node GRU update. Rows in registers; weights via wave-uniform
// loads (L1-broadcast / scalar). x transposed d->k order via in-place
// round-trip through the (dead) agg row. MODE 0: fuse s_att for next layer
// (weights Wnext = Ws of layer i+1). MODE 1: fuse final score (Wnext = Wf).
template<int MODE>
__global__ __launch_bounds__(256, 2) void node_kernel(
    const float* __restrict__ Wh,     // [64*64] this layer
    const float* __restrict__ Wih,    // [192*64]
    const float* __restrict__ Whh,    // [192*64]
    const float* __restrict__ bih,    // [192]
    const float* __restrict__ bhh,    // [192]
    const float* __restrict__ Wnext,  // MODE0: Ws[i+1] [8*64]; MODE1: Wf [64]
    float* __restrict__ h,            // [NNODE*64] in/out
    float* __restrict__ agg,          // [NNODE*64] in (clobbered as x scratch)
    float* __restrict__ s_att,        // MODE0 out [NNODE*8]
    float* __restrict__ scores)       // MODE1 out [NNODE]
{
    const int n = blockIdx.x * blockDim.x + threadIdx.x;
    if (n >= NNODE) return;
    float* arow = agg + (size_t)n * 64;
    float* hrow = h + (size_t)n * 64;

    // ---- load agg row (statically indexed) ----
    float g[64];
    {
        const float4* a4 = (const float4*)arow;
#pragma unroll
        for (int q = 0; q < 16; ++q) {
            float4 v = a4[q];
            g[4 * q] = v.x; g[4 * q + 1] = v.y; g[4 * q + 2] = v.z; g[4 * q + 3] = v.w;
        }
    }
    // ---- x = relu(g @ Wh^T), written back into arow (d-order) ----
#pragma unroll 2
    for (int d = 0; d < 64; ++d) {
        const float* wrow = Wh + d * 64;
        float acc = 0.0f;
#pragma unroll
        for (int k = 0; k < 64; ++k) acc = fmaf(g[k], wrow[k], acc);
        arow[d] = fmaxf(acc, 0.0f);
    }
    // ---- reload x (k-order static) and h row ----
    float x[64], hv[64];
    {
        const float4* a4 = (const float4*)arow;
        const float4* h4 = (const float4*)hrow;
#pragma unroll
        for (int q = 0; q < 16; ++q) {
            float4 v = a4[q];
            x[4 * q] = v.x; x[4 * q + 1] = v.y; x[4 * q + 2] = v.z; x[4 * q + 3] = v.w;
            float4 w = h4[q];
            hv[4 * q] = w.x; hv[4 * q + 1] = w.y; hv[4 * q + 2] = w.z; hv[4 * q + 3] = w.w;
        }
    }
    // ---- GRU + fused epilogue ----
    float sacc[8] = {0, 0, 0, 0, 0, 0, 0, 0};
    float sc = 0.0f;
#pragma unroll 1
    for (int d = 0; d < 64; ++d) {
        float ir = bih[d], iz = bih[64 + d], in_ = bih[128 + d];
        float hr = bhh[d], hz = bhh[64 + d], hn = bhh[128 + d];
        const float* wi0 = Wih + d * 64;
        const float* wi1 = Wih + (64 + d) * 64;
        const float* wi2 = Wih + (128 + d) * 64;
        const float* wh0 = Whh + d * 64;
        const float* wh1 = Whh + (64 + d) * 64;
        const float* wh2 = Whh + (128 + d) * 64;
#pragma unroll
        for (int k = 0; k < 64; ++k) {
            ir = fmaf(x[k], wi0[k], ir);
            iz = fmaf(x[k], wi1[k], iz);
            in_ = fmaf(x[k], wi2[k], in_);
            hr = fmaf(hv[k], wh0[k], hr);
            hz = fmaf(hv[k], wh1[k], hz);
            hn = fmaf(hv[k], wh2[k], hn);
        }
        const float r = sigmoidf_(ir + hr);
        const float z = sigmoidf_(iz + hz);
        const float nn = tanhf_(in_ + r * hn);
        const float hnew = (1.0f - z) * nn + z * hv[d];
        hrow[d] = hnew;
        if (MODE == 0) {
#pragma unroll
            for (int a = 0; a < 8; ++a)
                sacc[a] = fmaf(hnew, Wnext[a * 64 + d], sacc[a]);
        } else {
            sc = fmaf(hnew, Wnext[d], sc);
        }
    }
    if (MODE == 0) {
        float4* s4 = (float4*)(s_att + (size_t)n * 8);
        s4[0] = make_float4(sacc[0], sacc[1], sacc[2], sacc[3]);
        s4[1] = make_float4(sacc[4], sacc[5], sacc[6], sacc[7]);
    } else {
        scores[n] = sc;
    }
}

__global__ void scatter_max_kernel(const int* __restrict__ nq, const int* __restrict__ ne,
                                   int* __restrict__ winner)
{
    int n = blockIdx.x * blockDim.x + threadIdx.x;
    if (n < NNODE) {
        int pos = nq[n] * ENTC + ne[n];
        atomicMax(&winner[pos], n);
    }
}

__global__ void scatter_write_kernel(const int* __restrict__ nq, const int* __restrict__ ne,
                                     const int* __restrict__ winner,
                                     const float* __restrict__ scores,
                                     float* __restrict__ out)
{
    int n = blockIdx.x * blockDim.x + threadIdx.x;
    if (n < NNODE) {
        int pos = nq[n] * ENTC + ne[n];
        if (winner[pos] == n) out[pos] = scores[n];
    }
}

extern "C" void kernel_launch(void* const* d_in, const int* in_sizes, int n_in,
                              void* d_out, int out_size, void* d_ws, size_t ws_size,
                              hipStream_t stream)
{
    const int* relation  = (const int*)d_in[0];
    const int* r_idx     = (const int*)d_in[1];
    const int* rel       = (const int*)d_in[2];
    const int* sub       = (const int*)d_in[3];
    const int* obj       = (const int*)d_in[4];
    // d_in[5] = idx (identity permutation; index_copy is a no-op) — unused
    const int* nodes_q   = (const int*)d_in[6];
    const int* nodes_ent = (const int*)d_in[7];
    const float* rela    = (const float*)d_in[8];
    const float* Ws      = (const float*)d_in[9];
    const float* Wr      = (const float*)d_in[10];
    const float* Wqr     = (const float*)d_in[11];
    const float* Wqrb    = (const float*)d_in[12];
    const float* walw    = (const float*)d_in[13];
    const float* walb    = (const float*)d_in[14];
    const float* Wh      = (const float*)d_in[15];
    const float* gWih    = (const float*)d_in[16];
    const float* gWhh    = (const float*)d_in[17];
    const float* gbih    = (const float*)d_in[18];
    const float* gbhh    = (const float*)d_in[19];
    const float* Wf      = (const float*)d_in[20];

    float* ws     = (float*)d_ws;
    float* scores = ws;                      // NNODE floats (padded to 102400)
    float* h      = ws + 102400;             // NNODE*DD
    float* agg    = h + NNODE * DD;          // NNODE*DD
    int*   winner = (int*)(ws + 102400);     // QE ints; overlays h/agg AFTER scores done
    float* out    = (float*)d_out;

    // d_out doubles as scratch during the layers (dead until final scatter;
    // zero-filled just before the winner pass). Total ~3.1M floats << QE (10M).
    float* alpha    = (float*)d_out;          // EE
    float* s_att    = alpha + EE;             // NNODE*8
    float* r_att    = s_att + NNODE * 8;      // 461*8
    float* qr_att   = r_att + NR2C * 8;       // 1000*8
    int*   counts   = (int*)(qr_att + QQ * 8);// NNODE
    int*   cursor   = counts + NNODE;         // NNODE
    int*   partials = cursor + NNODE;         // 128
    int*   eidx     = partials + 128;         // EE

    fill_f32<<<2048, 256, 0, stream>>>(h, NNODE * DD, 0.0f);
    fill_f32<<<512, 256, 0, stream>>>(s_att, NNODE * 8, 0.0f);  // layer0: h=0 -> s_att=0

    for (int i = 0; i < LL; ++i) {
        const float* emb = rela + i * NR2C * DD;
        rqatt_kernel<<<184, 256, 0, stream>>>(relation, emb,
            Wr + i * AAT * DD, Wqr + i * AAT * DD, Wqrb + i * AAT, r_att, qr_att);
        fill_i32<<<128, 256, 0, stream>>>(counts, NNODE, 0);
        alpha_hist_kernel<<<(EE + 255) / 256, 256, 0, stream>>>(
            sub + i * EE, rel + i * EE, r_idx + i * EE, obj + i * EE,
            s_att, r_att, qr_att, walw + i * AAT, walb + i, alpha, counts);
        scan_block_kernel<<<SCAN_NB, 1024, 0, stream>>>(counts, cursor, partials);
        scan_partials_kernel<<<1, 128, 0, stream>>>(partials);
        scan_add_kernel<<<(NNODE + 255) / 256, 256, 0, stream>>>(cursor, partials);
        bucket_kernel<<<(EE + 255) / 256, 256, 0, stream>>>(obj + i * EE, cursor, eidx);
        aggregate_kernel<<<(NNODE * 64 + 255) / 256, 256, 0, stream>>>(
            sub + i * EE, rel + i * EE, eidx, cursor, counts, alpha, h, emb, agg);
        if (i < LL - 1) {
            node_kernel<0><<<(NNODE + 255) / 256, 256, 0, stream>>>(
                Wh + i * DD * DD, gWih, gWhh, gbih, gbhh,
                Ws + (i + 1) * AAT * DD, h, agg, s_att, scores);
        } else {
            node_kernel<1><<<(NNODE + 255) / 256, 256, 0, stream>>>(
                Wh + i * DD * DD, gWih, gWhh, gbih, gbhh,
                Wf, h, agg, s_att, scores);
        }
    }

    // h/agg and the d_out scratch are dead now.
    fill_f32<<<2048, 256, 0, stream>>>(out, QE, 0.0f);
    fill_i32<<<2048, 256, 0, stream>>>(winner, QE, -1);
    scatter_max_kernel<<<(NNODE + 255) / 256, 256, 0, stream>>>(nodes_q, nodes_ent, winner);
    scatter_write_kernel<<<(NNODE + 255) / 256, 256, 0, stream>>>(nodes_q, nodes_ent, winner, scores, out);
}